// Round 14
// baseline (15160.216 us; speedup 1.0000x reference)
//
#include <hip/hip_runtime.h>
#include <hip/hip_bf16.h>

// LSTM: B=64, S=512, H=768, L=2. Persistent scan per layer, 16 waves/WG.
// ROUND 14: sync stripped to ONE barrier per step.
//   waves 0-11 (h): self-poll group counter cnt[grp][s-1]==64 (1 MALL line),
//                   then K=64 slice GEMM -> hpart[s&1] (double-buffered).
//   waves 12-14 (x): x-proj TWO steps ahead into 4-slot ring (pure slack);
//                   after the barrier they finalize gates/state, store h,
//                   drain, and the last of the 3 bumps cnt (LDS election).
//   wave 15: idle (arrives at barrier).
// Per step: poll -> loads -> b2 -> finalize -> bump. No poller wave, no b1/b3.
// Weights pre-split (hi|lo uint4) per-wave-slice, L2-resident (2.3MB/XCD).
// h exchange: MALL-bypass stores + vmcnt ack + counter; consumers plain
// cached loads on write-once streams (round-5-proven) or bypass ring (small ws).

#define HID 768
#define FH  3072
#define SEQ 512
#define BAT 64
#define GB  16
#define NWG 256
#define TPB 1024         // 16 waves

typedef __attribute__((ext_vector_type(8))) __bf16 bf16x8;
typedef __attribute__((ext_vector_type(4))) float f32x4;
typedef unsigned int u32;
typedef unsigned long long u64;

__device__ __forceinline__ float sigm(float z) { return 1.f / (1.f + __expf(-z)); }
__device__ __forceinline__ float tanh_fast(float x) {
  float a = fabsf(x);
  float e = __expf(-2.f * a);
  float t = (1.f - e) / (1.f + e);
  return copysignf(t, x);
}
__device__ __forceinline__ unsigned short bfbits(__bf16 b) {
  union { __bf16 b; unsigned short s; } u; u.b = b; return u.s;
}
__device__ __forceinline__ __bf16 bits2bf(unsigned short s) {
  union { unsigned short s; __bf16 b; } u; u.s = s; return u.b;
}
__device__ __forceinline__ u32 packsplit(float v) {
  __bf16 h = (__bf16)v;
  __bf16 l = (__bf16)(v - (float)h);
  return ((u32)bfbits(h) << 16) | (u32)bfbits(l);
}
__device__ __forceinline__ void split8(const float* p, bf16x8& hi, bf16x8& lo) {
  const float4* q = (const float4*)p;
  float4 a = q[0], b = q[1];
  float v[8] = {a.x, a.y, a.z, a.w, b.x, b.y, b.z, b.w};
#pragma unroll
  for (int i = 0; i < 8; ++i) {
    __bf16 h = (__bf16)v[i];
    hi[i] = h;
    lo[i] = (__bf16)(v[i] - (float)h);
  }
}
__device__ __forceinline__ void unpack8(const u32 w[8], bf16x8& hi, bf16x8& lo) {
#pragma unroll
  for (int i = 0; i < 8; ++i) {
    hi[i] = bits2bf((unsigned short)(w[i] >> 16));
    lo[i] = bits2bf((unsigned short)(w[i] & 0xffffu));
  }
}
__device__ __forceinline__ bf16x8 q2b(uint4 q) {
  union { uint4 q; bf16x8 v; } u; u.q = q; return u.v;
}
__device__ __forceinline__ uint4 b2q(bf16x8 v) {
  union { bf16x8 v; uint4 q; } u; u.v = v; return u.q;
}

// ---- prep: split Wih+Whh (both layers) into per-wave slice layout ----
__global__ void pack_w(const float* __restrict__ Wih,
                       const float* __restrict__ Whh,
                       u32* __restrict__ wpk) {
  int g = blockIdx.x * blockDim.x + threadIdx.x;
  const int NT = 2 * 9216 * 64;
  if (g >= NT) return;
  int lane = g & 63;
  int sl = g >> 6;
  int region = sl / 9216;          // 0 = wih, 1 = whh
  int sr = sl % 9216;
  int l15 = lane & 15, lhi = lane >> 4;
  int k, wid, layer;
  const float* W;
  if (region == 0) {
    int c  = sr % 8;
    int xw = (sr / 24) % 3;
    wid    = (sr / 72) % 64;
    layer  = sr / 4608;
    k = xw*256 + c*32 + lhi*8;
    W = Wih + (size_t)layer*FH*HID;
  } else {
    int c  = sr % 2;
    int j  = (sr / 6) % 12;
    wid    = (sr / 72) % 64;
    layer  = sr / 4608;
    k = j*64 + c*32 + lhi*8;
    W = Whh + (size_t)layer*FH*HID;
  }
  int t = (region == 0) ? (sr / 8) % 3 : (sr / 2) % 3;
  int row = (l15 & 3)*HID + wid*12 + t*4 + (l15 >> 2);
  bf16x8 hi, lo;
  split8(W + (size_t)row*HID + k, hi, lo);
  u32* dst = wpk + ((size_t)region*9216 + sr)*512 + lane*8;
  *(uint4*)dst       = b2q(hi);
  *(uint4*)(dst + 4) = b2q(lo);
}

#define MFMA16 __builtin_amdgcn_mfma_f32_16x16x32_bf16

template<int XFMT, int WRITE_OUT, int RING>
__attribute__((amdgpu_waves_per_eu(4, 4)))
__global__ void __launch_bounds__(TPB)
lstm_scan(const float* __restrict__ xf,
          const u32* __restrict__ xp,
          const float* __restrict__ mask,
          const u32* __restrict__ wipk,
          const u32* __restrict__ whpk,
          const float* __restrict__ bih,
          const float* __restrict__ bhh,
          u32* __restrict__ hdst,
          const u32* __restrict__ hsrc,
          float* __restrict__ out_f,
          float* __restrict__ hn, float* __restrict__ cn,
          int* __restrict__ cnt)          // layer base: [4 groups][SEQ], zeroed
{
  __shared__ f32x4 xring[4][3][3][64];    // 36864 B
  __shared__ f32x4 hpart[2][12][3][64];   // 73728 B
  __shared__ int   lfin[SEQ];             // 2048 B

  const int wg  = blockIdx.x;
  const int grp = wg >> 6;
  const int wid = wg & 63;
  const int tid = threadIdx.x;
  const int wv  = tid >> 6;
  const int l   = tid & 63;
  const int l15 = l & 15;
  const int lhi = l >> 4;

  const bool ish  = (wv < 12);
  const bool isxw = (wv >= 12 && wv < 15);
  const int j  = wv;
  const int xw = wv - 12;

  const int batch = grp*GB + l15;
  const u32* wbj = whpk + (size_t)(wid*12 + (ish  ? j  : 0))*6*512;
  const u32* wbx = wipk + (size_t)(wid*3  + (isxw ? xw : 0))*24*512;

  const int colO = wid*12 + (isxw ? xw : 0)*4 + lhi;
  float bias4[4] = {0.f, 0.f, 0.f, 0.f};
  if (isxw) {
#pragma unroll
    for (int r = 0; r < 4; ++r) bias4[r] = bih[r*HID + colO] + bhh[r*HID + colO];
  }
  const float* mrow = mask + batch*SEQ;
  int* gcnt = cnt + grp*SEQ;
  float cstate = 0.f;

  for (int i = tid; i < SEQ; i += TPB) lfin[i] = 0;

  auto xproj = [&](int sstep, int slot) {
    f32x4 a0{0.f,0.f,0.f,0.f}, a1{0.f,0.f,0.f,0.f}, a2{0.f,0.f,0.f,0.f};
#pragma unroll
    for (int c = 0; c < 8; ++c) {
      bf16x8 bhi, blo;
      if constexpr (XFMT == 0) {
        const float* src = xf + ((size_t)batch*SEQ + sstep)*HID + xw*256 + c*32 + lhi*8;
        split8(src, bhi, blo);
      } else {
        const u32* src = xp + ((size_t)sstep*BAT + batch)*HID + xw*256 + c*32 + lhi*8;
        uint4 A = *(const uint4*)src, B = *(const uint4*)(src + 4);
        u32 w[8] = {A.x,A.y,A.z,A.w,B.x,B.y,B.z,B.w};
        unpack8(w, bhi, blo);
      }
      {
        const uint4* wp = (const uint4*)(wbx + (size_t)(0*8 + c)*512 + l*8);
        bf16x8 Ah = q2b(wp[0]), Al = q2b(wp[1]);
        a0 = MFMA16(Ah, bhi, a0, 0,0,0); a0 = MFMA16(Al, bhi, a0, 0,0,0); a0 = MFMA16(Ah, blo, a0, 0,0,0);
      }
      {
        const uint4* wp = (const uint4*)(wbx + (size_t)(1*8 + c)*512 + l*8);
        bf16x8 Ah = q2b(wp[0]), Al = q2b(wp[1]);
        a1 = MFMA16(Ah, bhi, a1, 0,0,0); a1 = MFMA16(Al, bhi, a1, 0,0,0); a1 = MFMA16(Ah, blo, a1, 0,0,0);
      }
      {
        const uint4* wp = (const uint4*)(wbx + (size_t)(2*8 + c)*512 + l*8);
        bf16x8 Ah = q2b(wp[0]), Al = q2b(wp[1]);
        a2 = MFMA16(Ah, bhi, a2, 0,0,0); a2 = MFMA16(Al, bhi, a2, 0,0,0); a2 = MFMA16(Ah, blo, a2, 0,0,0);
      }
    }
    xring[slot][xw][0][l] = a0;
    xring[slot][xw][1][l] = a1;
    xring[slot][xw][2][l] = a2;
  };

  if (isxw) { xproj(0, 0); xproj(1, 1); }

#pragma unroll 1
  for (int s = 0; s < SEQ; ++s) {
    if (ish && s > 0) {
      const int* cp = gcnt + (s - 1);
      while (__hip_atomic_load(cp, __ATOMIC_RELAXED, __HIP_MEMORY_SCOPE_AGENT) < 64)
        __builtin_amdgcn_s_sleep(2);
      f32x4 a0{0.f,0.f,0.f,0.f}, a1{0.f,0.f,0.f,0.f}, a2{0.f,0.f,0.f,0.f};
#pragma unroll
      for (int c = 0; c < 2; ++c) {
        u32 w[8];
        if constexpr (RING) {
          const u64* sp = (const u64*)(hsrc + ((size_t)((s-1)&1)*BAT + batch)*HID + j*64 + c*32 + lhi*8);
          u64 qa = __hip_atomic_load(sp,   __ATOMIC_RELAXED, __HIP_MEMORY_SCOPE_AGENT);
          u64 qb = __hip_atomic_load(sp+1, __ATOMIC_RELAXED, __HIP_MEMORY_SCOPE_AGENT);
          u64 qc = __hip_atomic_load(sp+2, __ATOMIC_RELAXED, __HIP_MEMORY_SCOPE_AGENT);
          u64 qd = __hip_atomic_load(sp+3, __ATOMIC_RELAXED, __HIP_MEMORY_SCOPE_AGENT);
          w[0]=(u32)qa; w[1]=(u32)(qa>>32); w[2]=(u32)qb; w[3]=(u32)(qb>>32);
          w[4]=(u32)qc; w[5]=(u32)(qc>>32); w[6]=(u32)qd; w[7]=(u32)(qd>>32);
        } else {
          const u32* sp = hsrc + ((size_t)(s-1)*BAT + batch)*HID + j*64 + c*32 + lhi*8;
          uint4 A = *(const uint4*)sp, B = *(const uint4*)(sp + 4);
          w[0]=A.x; w[1]=A.y; w[2]=A.z; w[3]=A.w;
          w[4]=B.x; w[5]=B.y; w[6]=B.z; w[7]=B.w;
        }
        bf16x8 bhi, blo;
        unpack8(w, bhi, blo);
        {
          const uint4* wp = (const uint4*)(wbj + (size_t)(0*2 + c)*512 + l*8);
          bf16x8 Ah = q2b(wp[0]), Al = q2b(wp[1]);
          a0 = MFMA16(Ah, bhi, a0, 0,0,0); a0 = MFMA16(Al, bhi, a0, 0,0,0); a0 = MFMA16(Ah, blo, a0, 0,0,0);
        }
        {
          const uint4* wp = (const uint4*)(wbj + (size_t)(1*2 + c)*512 + l*8);
          bf16x8 Ah = q2b(wp[0]), Al = q2b(wp[1]);
          a1 = MFMA16(Ah, bhi, a1, 0,0,0); a1 = MFMA16(Al, bhi, a1, 0,0,0); a1 = MFMA16(Ah, blo, a1, 0,0,0);
        }
        {
          const uint4* wp = (const uint4*)(wbj + (size_t)(2*2 + c)*512 + l*8);
          bf16x8 Ah = q2b(wp[0]), Al = q2b(wp[1]);
          a2 = MFMA16(Ah, bhi, a2, 0,0,0); a2 = MFMA16(Al, bhi, a2, 0,0,0); a2 = MFMA16(Ah, blo, a2, 0,0,0);
        }
      }
      hpart[s & 1][j][0][l] = a0;
      hpart[s & 1][j][1][l] = a1;
      hpart[s & 1][j][2][l] = a2;
    }
    if (isxw && s + 2 < SEQ) xproj(s + 2, (s + 2) & 3);
    __syncthreads();   // the ONLY barrier per step

    if (isxw) {
      f32x4 z = xring[s & 3][0][xw][l] + xring[s & 3][1][xw][l] + xring[s & 3][2][xw][l];
      if (s > 0) {
#pragma unroll
        for (int jj = 0; jj < 12; ++jj) z = z + hpart[s & 1][jj][xw][l];
      }
      float zi = z[0] + bias4[0], zf = z[1] + bias4[1];
      float zg = z[2] + bias4[2], zo = z[3] + bias4[3];
      float iv = sigm(zi), fv = sigm(zf), gv = tanh_fast(zg), ov = sigm(zo);
      float c  = fv*cstate + iv*gv;
      float hv = ov * tanh_fast(c);
      float m  = mrow[s];
      hv *= m; c *= m; cstate = c;

      u32 hw = packsplit(hv);
      size_t wrow = RING ? ((size_t)(s & 1)*BAT + batch)*HID + colO
                         : ((size_t)s*BAT + batch)*HID + colO;
      __hip_atomic_store(hdst + wrow, hw,
                         __ATOMIC_RELAXED, __HIP_MEMORY_SCOPE_AGENT);
      if constexpr (WRITE_OUT) {
        __builtin_nontemporal_store(hv, out_f + ((size_t)batch*SEQ + s)*HID + colO);
      }
      if (s == SEQ - 1) {
        hn[batch*HID + colO] = hv;
        cn[batch*HID + colO] = c;
      }
      asm volatile("s_waitcnt vmcnt(0)" ::: "memory");
      if (l == 0) {
        int old = atomicAdd(&lfin[s], 1);
        if (old == 2)
          __hip_atomic_fetch_add(gcnt + s, 1,
                                 __ATOMIC_RELAXED, __HIP_MEMORY_SCOPE_AGENT);
      }
    }
  }
}

extern "C" void kernel_launch(void* const* d_in, const int* in_sizes, int n_in,
                              void* d_out, int out_size, void* d_ws, size_t ws_size,
                              hipStream_t stream) {
  const float* x    = (const float*)d_in[0];
  const float* mask = (const float*)d_in[1];
  const float* Wih  = (const float*)d_in[2];
  const float* Whh  = (const float*)d_in[3];
  const float* bih  = (const float*)d_in[4];
  const float* bhh  = (const float*)d_in[5];
  float* out = (float*)d_out;

  char* ws = (char*)d_ws;
  const size_t WPK_B   = (size_t)2*9216*512*4;       // 37,748,736
  const size_t STREAM_B = (size_t)SEQ*BAT*HID*4;     // 100,663,296
  const size_t RING_B  = (size_t)2*BAT*HID*4;        // 393,216

  u32* wpk = (u32*)ws;
  u32* opk = (u32*)(ws + WPK_B);                     // L0 h-stream = L1 input
  const bool big = ws_size >= WPK_B + 2*STREAM_B + 65536;
  u32* h1  = (u32*)(ws + WPK_B + STREAM_B);          // L1 h store
  int* cnt = big ? (int*)(ws + WPK_B + 2*STREAM_B)
                 : (int*)(ws + WPK_B + STREAM_B + RING_B);
  // cnt layout: [2 layers][4 groups][SEQ]

  (void)hipMemsetAsync(cnt, 0, 2*4*SEQ*sizeof(int), stream);
  pack_w<<<4608, 256, 0, stream>>>(Wih, Whh, wpk);

  float* hn = out + 25165824;                        // [2][64][768]
  float* cn = out + 25165824 + 98304;

  const u32* wipk0 = wpk;
  const u32* wipk1 = wpk + (size_t)4608*512;
  const u32* whpk0 = wpk + (size_t)9216*512;
  const u32* whpk1 = wpk + (size_t)13824*512;

  lstm_scan<0, 0, 0><<<dim3(NWG), dim3(TPB), 0, stream>>>(
      x, nullptr, mask, wipk0, whpk0, bih, bhh,
      opk, opk, nullptr, hn, cn, cnt);

  if (big) {
    lstm_scan<1, 1, 0><<<dim3(NWG), dim3(TPB), 0, stream>>>(
        nullptr, opk, mask, wipk1, whpk1, bih + FH, bhh + FH,
        h1, h1, out, hn + 49152, cn + 49152, cnt + 4*SEQ);
  } else {
    lstm_scan<1, 1, 1><<<dim3(NWG), dim3(TPB), 0, stream>>>(
        nullptr, opk, mask, wipk1, whpk1, bih + FH, bhh + FH,
        h1, h1, out, hn + 49152, cn + 49152, cnt + 4*SEQ);
  }
}

// Round 15
// 14868.169 us; speedup vs baseline: 1.0196x; 1.0196x over previous
//
#include <hip/hip_runtime.h>
#include <hip/hip_bf16.h>

// LSTM: B=64, S=512, H=768, L=2. Persistent scan per layer, 16 waves/WG.
// ROUND 15: ZERO in-loop barriers; x-projection fully decoupled.
//   waves 0-11 (h): preload weights -> poll (j0: global cnt, others: LDS
//                   release flag) -> h loads + MFMA -> hpart + hcnt[s]++.
//   waves 12-14 (x): FREE-RUNNING, up to 4 steps ahead into xring, throttled
//                   only by fdone[t-4]. Their LLC x-latency is pure slack.
//   wave 15 (fin):  poll xrdy[s] (+hcnt[s]) -> sum -> fdone[s]=1 -> gates ->
//                   bypass h store -> vmcnt(0) -> global cnt[s]++.
// All intra-WG sync = LDS acquire/release flag words (no __syncthreads in loop).
// Weights pre-split per-wave-slice (round-13/14 pack_w, verified).
// h exchange: MALL-bypass stores + vmcnt ack + counter; consumers plain cached
// loads on write-once streams (proven rounds 5-14) or bypass ring (small ws).

#define HID 768
#define FH  3072
#define SEQ 512
#define BAT 64
#define GB  16
#define NWG 256
#define TPB 1024         // 16 waves

typedef __attribute__((ext_vector_type(8))) __bf16 bf16x8;
typedef __attribute__((ext_vector_type(4))) float f32x4;
typedef unsigned int u32;
typedef unsigned long long u64;

__device__ __forceinline__ float sigm(float z) { return 1.f / (1.f + __expf(-z)); }
__device__ __forceinline__ float tanh_fast(float x) {
  float a = fabsf(x);
  float e = __expf(-2.f * a);
  float t = (1.f - e) / (1.f + e);
  return copysignf(t, x);
}
__device__ __forceinline__ unsigned short bfbits(__bf16 b) {
  union { __bf16 b; unsigned short s; } u; u.b = b; return u.s;
}
__device__ __forceinline__ __bf16 bits2bf(unsigned short s) {
  union { unsigned short s; __bf16 b; } u; u.s = s; return u.b;
}
__device__ __forceinline__ u32 packsplit(float v) {
  __bf16 h = (__bf16)v;
  __bf16 l = (__bf16)(v - (float)h);
  return ((u32)bfbits(h) << 16) | (u32)bfbits(l);
}
__device__ __forceinline__ void split8(const float* p, bf16x8& hi, bf16x8& lo) {
  const float4* q = (const float4*)p;
  float4 a = q[0], b = q[1];
  float v[8] = {a.x, a.y, a.z, a.w, b.x, b.y, b.z, b.w};
#pragma unroll
  for (int i = 0; i < 8; ++i) {
    __bf16 h = (__bf16)v[i];
    hi[i] = h;
    lo[i] = (__bf16)(v[i] - (float)h);
  }
}
__device__ __forceinline__ void unpack8(const u32 w[8], bf16x8& hi, bf16x8& lo) {
#pragma unroll
  for (int i = 0; i < 8; ++i) {
    hi[i] = bits2bf((unsigned short)(w[i] >> 16));
    lo[i] = bits2bf((unsigned short)(w[i] & 0xffffu));
  }
}
__device__ __forceinline__ bf16x8 q2b(uint4 q) {
  union { uint4 q; bf16x8 v; } u; u.q = q; return u.v;
}
__device__ __forceinline__ uint4 b2q(bf16x8 v) {
  union { bf16x8 v; uint4 q; } u; u.v = v; return u.q;
}

// ---- prep: split Wih+Whh (both layers) into per-wave slice layout ----
// (identical to round 13/14 -- numerics verified on HW)
__global__ void pack_w(const float* __restrict__ Wih,
                       const float* __restrict__ Whh,
                       u32* __restrict__ wpk) {
  int g = blockIdx.x * blockDim.x + threadIdx.x;
  const int NT = 2 * 9216 * 64;
  if (g >= NT) return;
  int lane = g & 63;
  int sl = g >> 6;
  int region = sl / 9216;          // 0 = wih, 1 = whh
  int sr = sl % 9216;
  int l15 = lane & 15, lhi = lane >> 4;
  int k, wid, layer;
  const float* W;
  if (region == 0) {
    int c  = sr % 8;
    int xw = (sr / 24) % 3;
    wid    = (sr / 72) % 64;
    layer  = sr / 4608;
    k = xw*256 + c*32 + lhi*8;
    W = Wih + (size_t)layer*FH*HID;
  } else {
    int c  = sr % 2;
    int j  = (sr / 6) % 12;
    wid    = (sr / 72) % 64;
    layer  = sr / 4608;
    k = j*64 + c*32 + lhi*8;
    W = Whh + (size_t)layer*FH*HID;
  }
  int t = (region == 0) ? (sr / 8) % 3 : (sr / 2) % 3;
  int row = (l15 & 3)*HID + wid*12 + t*4 + (l15 >> 2);
  bf16x8 hi, lo;
  split8(W + (size_t)row*HID + k, hi, lo);
  u32* dst = wpk + ((size_t)region*9216 + sr)*512 + lane*8;
  *(uint4*)dst       = b2q(hi);
  *(uint4*)(dst + 4) = b2q(lo);
}

#define MFMA16 __builtin_amdgcn_mfma_f32_16x16x32_bf16
#define LD_ACQ(p)  __hip_atomic_load((p), __ATOMIC_ACQUIRE, __HIP_MEMORY_SCOPE_WORKGROUP)
#define ST_REL(p,v) __hip_atomic_store((p), (v), __ATOMIC_RELEASE, __HIP_MEMORY_SCOPE_WORKGROUP)
#define ADD_REL(p)  __hip_atomic_fetch_add((p), 1, __ATOMIC_RELEASE, __HIP_MEMORY_SCOPE_WORKGROUP)

template<int XFMT, int WRITE_OUT, int RING>
__attribute__((amdgpu_waves_per_eu(4, 4)))
__global__ void __launch_bounds__(TPB)
lstm_scan(const float* __restrict__ xf,
          const u32* __restrict__ xp,
          const float* __restrict__ mask,
          const u32* __restrict__ wipk,
          const u32* __restrict__ whpk,
          const float* __restrict__ bih,
          const float* __restrict__ bhh,
          u32* __restrict__ hdst,
          const u32* __restrict__ hsrc,
          float* __restrict__ out_f,
          float* __restrict__ hn, float* __restrict__ cn,
          int* __restrict__ cnt)          // layer base: [4 groups][SEQ], zeroed
{
  __shared__ f32x4 xring[4][3][3][64];    // 36864 B [slot][xw][tile][lane]
  __shared__ f32x4 hpart[2][12][3][64];   // 73728 B [buf][j][tile][lane]
  __shared__ int hcnt[SEQ];               // 2048 B
  __shared__ int xrdy[SEQ];               // 2048 B
  __shared__ int fdone[SEQ];              // 2048 B
  __shared__ int grel[SEQ];               // 2048 B

  const int wg  = blockIdx.x;
  const int grp = wg >> 6;
  const int wid = wg & 63;
  const int tid = threadIdx.x;
  const int wv  = tid >> 6;
  const int l   = tid & 63;
  const int l15 = l & 15;
  const int lhi = l >> 4;

  const int batch = grp*GB + l15;
  int* gcnt = cnt + grp*SEQ;

  for (int i = tid; i < SEQ; i += TPB) {
    hcnt[i] = 0; xrdy[i] = 0; fdone[i] = 0; grel[i] = 0;
  }
  __syncthreads();   // flags zeroed (only barrier in the kernel)

  if (wv < 12) {
    // ================= h-wave: K=64 slice j =================
    const int j = wv;
    const u32* wbj = whpk + (size_t)(wid*12 + j)*6*512;
#pragma unroll 1
    for (int s = 1; s < SEQ; ++s) {
      // preload this step's weights BEFORE the poll (L2-hit, off-path)
      uint4 wa[12];
#pragma unroll
      for (int c = 0; c < 2; ++c)
#pragma unroll
        for (int t = 0; t < 3; ++t) {
          const uint4* wp = (const uint4*)(wbj + (size_t)(t*2 + c)*512 + l*8);
          wa[(c*3 + t)*2]     = wp[0];
          wa[(c*3 + t)*2 + 1] = wp[1];
        }
      // poll: j0 watches the global counter, releases peers via LDS
      if (j == 0) {
        const int* cp = gcnt + (s - 1);
        while (__hip_atomic_load(cp, __ATOMIC_RELAXED, __HIP_MEMORY_SCOPE_AGENT) < 64)
          __builtin_amdgcn_s_sleep(2);
        if (l == 0) ST_REL(&grel[s], 1);
      } else {
        while (LD_ACQ(&grel[s]) == 0) __builtin_amdgcn_s_sleep(1);
      }
      // h loads + MFMA
      f32x4 a0{0.f,0.f,0.f,0.f}, a1{0.f,0.f,0.f,0.f}, a2{0.f,0.f,0.f,0.f};
#pragma unroll
      for (int c = 0; c < 2; ++c) {
        u32 w[8];
        if constexpr (RING) {
          const u64* sp = (const u64*)(hsrc + ((size_t)((s-1)&1)*BAT + batch)*HID + j*64 + c*32 + lhi*8);
          u64 qa = __hip_atomic_load(sp,   __ATOMIC_RELAXED, __HIP_MEMORY_SCOPE_AGENT);
          u64 qb = __hip_atomic_load(sp+1, __ATOMIC_RELAXED, __HIP_MEMORY_SCOPE_AGENT);
          u64 qc = __hip_atomic_load(sp+2, __ATOMIC_RELAXED, __HIP_MEMORY_SCOPE_AGENT);
          u64 qd = __hip_atomic_load(sp+3, __ATOMIC_RELAXED, __HIP_MEMORY_SCOPE_AGENT);
          w[0]=(u32)qa; w[1]=(u32)(qa>>32); w[2]=(u32)qb; w[3]=(u32)(qb>>32);
          w[4]=(u32)qc; w[5]=(u32)(qc>>32); w[6]=(u32)qd; w[7]=(u32)(qd>>32);
        } else {
          const u32* sp = hsrc + ((size_t)(s-1)*BAT + batch)*HID + j*64 + c*32 + lhi*8;
          uint4 A = *(const uint4*)sp, B = *(const uint4*)(sp + 4);
          w[0]=A.x; w[1]=A.y; w[2]=A.z; w[3]=A.w;
          w[4]=B.x; w[5]=B.y; w[6]=B.z; w[7]=B.w;
        }
        bf16x8 bhi, blo;
        unpack8(w, bhi, blo);
        {
          bf16x8 Ah = q2b(wa[(c*3+0)*2]), Al = q2b(wa[(c*3+0)*2+1]);
          a0 = MFMA16(Ah, bhi, a0, 0,0,0); a0 = MFMA16(Al, bhi, a0, 0,0,0); a0 = MFMA16(Ah, blo, a0, 0,0,0);
        }
        {
          bf16x8 Ah = q2b(wa[(c*3+1)*2]), Al = q2b(wa[(c*3+1)*2+1]);
          a1 = MFMA16(Ah, bhi, a1, 0,0,0); a1 = MFMA16(Al, bhi, a1, 0,0,0); a1 = MFMA16(Ah, blo, a1, 0,0,0);
        }
        {
          bf16x8 Ah = q2b(wa[(c*3+2)*2]), Al = q2b(wa[(c*3+2)*2+1]);
          a2 = MFMA16(Ah, bhi, a2, 0,0,0); a2 = MFMA16(Al, bhi, a2, 0,0,0); a2 = MFMA16(Ah, blo, a2, 0,0,0);
        }
      }
      hpart[s & 1][j][0][l] = a0;
      hpart[s & 1][j][1][l] = a1;
      hpart[s & 1][j][2][l] = a2;
      asm volatile("s_waitcnt lgkmcnt(0)" ::: "memory");
      if (l == 0) (void)ADD_REL(&hcnt[s]);
    }
  } else if (wv < 15) {
    // ================= x-wave: free-running K=256 slice =================
    const int xw = wv - 12;
    const u32* wbx = wipk + (size_t)(wid*3 + xw)*24*512;
#pragma unroll 1
    for (int t = 0; t < SEQ; ++t) {
      if (t >= 4)
        while (LD_ACQ(&fdone[t - 4]) == 0) __builtin_amdgcn_s_sleep(1);
      f32x4 a0{0.f,0.f,0.f,0.f}, a1{0.f,0.f,0.f,0.f}, a2{0.f,0.f,0.f,0.f};
#pragma unroll
      for (int c = 0; c < 8; ++c) {
        bf16x8 bhi, blo;
        if constexpr (XFMT == 0) {
          const float* src = xf + ((size_t)batch*SEQ + t)*HID + xw*256 + c*32 + lhi*8;
          split8(src, bhi, blo);
        } else {
          const u32* src = xp + ((size_t)t*BAT + batch)*HID + xw*256 + c*32 + lhi*8;
          uint4 A = *(const uint4*)src, B = *(const uint4*)(src + 4);
          u32 w[8] = {A.x,A.y,A.z,A.w,B.x,B.y,B.z,B.w};
          unpack8(w, bhi, blo);
        }
        {
          const uint4* wp = (const uint4*)(wbx + (size_t)(0*8 + c)*512 + l*8);
          bf16x8 Ah = q2b(wp[0]), Al = q2b(wp[1]);
          a0 = MFMA16(Ah, bhi, a0, 0,0,0); a0 = MFMA16(Al, bhi, a0, 0,0,0); a0 = MFMA16(Ah, blo, a0, 0,0,0);
        }
        {
          const uint4* wp = (const uint4*)(wbx + (size_t)(1*8 + c)*512 + l*8);
          bf16x8 Ah = q2b(wp[0]), Al = q2b(wp[1]);
          a1 = MFMA16(Ah, bhi, a1, 0,0,0); a1 = MFMA16(Al, bhi, a1, 0,0,0); a1 = MFMA16(Ah, blo, a1, 0,0,0);
        }
        {
          const uint4* wp = (const uint4*)(wbx + (size_t)(2*8 + c)*512 + l*8);
          bf16x8 Ah = q2b(wp[0]), Al = q2b(wp[1]);
          a2 = MFMA16(Ah, bhi, a2, 0,0,0); a2 = MFMA16(Al, bhi, a2, 0,0,0); a2 = MFMA16(Ah, blo, a2, 0,0,0);
        }
      }
      const int slot = t & 3;
      xring[slot][xw][0][l] = a0;
      xring[slot][xw][1][l] = a1;
      xring[slot][xw][2][l] = a2;
      asm volatile("s_waitcnt lgkmcnt(0)" ::: "memory");
      if (l == 0) (void)ADD_REL(&xrdy[t]);
    }
  } else {
    // ================= finalize wave =================
    float cst0 = 0.f, cst1 = 0.f, cst2 = 0.f;
    const int c0 = wid*12 + 0*4 + lhi;
    const int c1 = wid*12 + 1*4 + lhi;
    const int c2 = wid*12 + 2*4 + lhi;
    float b0[4], b1[4], b2[4];
#pragma unroll
    for (int r = 0; r < 4; ++r) {
      b0[r] = bih[r*HID + c0] + bhh[r*HID + c0];
      b1[r] = bih[r*HID + c1] + bhh[r*HID + c1];
      b2[r] = bih[r*HID + c2] + bhh[r*HID + c2];
    }
    const float* mrow = mask + batch*SEQ;
#pragma unroll 1
    for (int s = 0; s < SEQ; ++s) {
      while (LD_ACQ(&xrdy[s]) < 3) __builtin_amdgcn_s_sleep(1);
      if (s > 0)
        while (LD_ACQ(&hcnt[s]) < 12) __builtin_amdgcn_s_sleep(1);
      const int slot = s & 3;
      f32x4 z0 = xring[slot][0][0][l] + xring[slot][1][0][l] + xring[slot][2][0][l];
      f32x4 z1 = xring[slot][0][1][l] + xring[slot][1][1][l] + xring[slot][2][1][l];
      f32x4 z2 = xring[slot][0][2][l] + xring[slot][1][2][l] + xring[slot][2][2][l];
      if (s > 0) {
#pragma unroll
        for (int j = 0; j < 12; ++j) {
          z0 = z0 + hpart[s & 1][j][0][l];
          z1 = z1 + hpart[s & 1][j][1][l];
          z2 = z2 + hpart[s & 1][j][2][l];
        }
      }
      asm volatile("s_waitcnt lgkmcnt(0)" ::: "memory");
      if (l == 0) ST_REL(&fdone[s], 1);   // xring slot consumed -> unblock x

      float m = mrow[s];
      float hv0, hv1, hv2, cc0, cc1, cc2;
      {
        float zi = z0[0]+b0[0], zf = z0[1]+b0[1], zg = z0[2]+b0[2], zo = z0[3]+b0[3];
        float iv = sigm(zi), fv = sigm(zf), gv = tanh_fast(zg), ov = sigm(zo);
        cc0 = (fv*cst0 + iv*gv) * m; hv0 = ov * tanh_fast(fv*cst0 + iv*gv) * m; cst0 = cc0;
      }
      {
        float zi = z1[0]+b1[0], zf = z1[1]+b1[1], zg = z1[2]+b1[2], zo = z1[3]+b1[3];
        float iv = sigm(zi), fv = sigm(zf), gv = tanh_fast(zg), ov = sigm(zo);
        cc1 = (fv*cst1 + iv*gv) * m; hv1 = ov * tanh_fast(fv*cst1 + iv*gv) * m; cst1 = cc1;
      }
      {
        float zi = z2[0]+b2[0], zf = z2[1]+b2[1], zg = z2[2]+b2[2], zo = z2[3]+b2[3];
        float iv = sigm(zi), fv = sigm(zf), gv = tanh_fast(zg), ov = sigm(zo);
        cc2 = (fv*cst2 + iv*gv) * m; hv2 = ov * tanh_fast(fv*cst2 + iv*gv) * m; cst2 = cc2;
      }

      size_t rowb = RING ? ((size_t)(s & 1)*BAT + batch)*HID
                         : ((size_t)s*BAT + batch)*HID;
      __hip_atomic_store(hdst + rowb + c0, packsplit(hv0), __ATOMIC_RELAXED, __HIP_MEMORY_SCOPE_AGENT);
      __hip_atomic_store(hdst + rowb + c1, packsplit(hv1), __ATOMIC_RELAXED, __HIP_MEMORY_SCOPE_AGENT);
      __hip_atomic_store(hdst + rowb + c2, packsplit(hv2), __ATOMIC_RELAXED, __HIP_MEMORY_SCOPE_AGENT);
      if constexpr (WRITE_OUT) {
        size_t ob = ((size_t)batch*SEQ + s)*HID;
        __builtin_nontemporal_store(hv0, out_f + ob + c0);
        __builtin_nontemporal_store(hv1, out_f + ob + c1);
        __builtin_nontemporal_store(hv2, out_f + ob + c2);
      }
      if (s == SEQ - 1) {
        hn[batch*HID + c0] = hv0; hn[batch*HID + c1] = hv1; hn[batch*HID + c2] = hv2;
        cn[batch*HID + c0] = cc0; cn[batch*HID + c1] = cc1; cn[batch*HID + c2] = cc2;
      }
      asm volatile("s_waitcnt vmcnt(0)" ::: "memory");  // h at MALL
      if (l == 0)
        __hip_atomic_fetch_add(gcnt + s, 1, __ATOMIC_RELAXED, __HIP_MEMORY_SCOPE_AGENT);
    }
  }
}

extern "C" void kernel_launch(void* const* d_in, const int* in_sizes, int n_in,
                              void* d_out, int out_size, void* d_ws, size_t ws_size,
                              hipStream_t stream) {
  const float* x    = (const float*)d_in[0];
  const float* mask = (const float*)d_in[1];
  const float* Wih  = (const float*)d_in[2];
  const float* Whh  = (const float*)d_in[3];
  const float* bih  = (const float*)d_in[4];
  const float* bhh  = (const float*)d_in[5];
  float* out = (float*)d_out;

  char* ws = (char*)d_ws;
  const size_t WPK_B   = (size_t)2*9216*512*4;       // 37,748,736
  const size_t STREAM_B = (size_t)SEQ*BAT*HID*4;     // 100,663,296
  const size_t RING_B  = (size_t)2*BAT*HID*4;        // 393,216

  u32* wpk = (u32*)ws;
  u32* opk = (u32*)(ws + WPK_B);                     // L0 h-stream = L1 input
  const bool big = ws_size >= WPK_B + 2*STREAM_B + 65536;
  u32* h1  = (u32*)(ws + WPK_B + STREAM_B);
  int* cnt = big ? (int*)(ws + WPK_B + 2*STREAM_B)
                 : (int*)(ws + WPK_B + STREAM_B + RING_B);
  // cnt layout: [2 layers][4 groups][SEQ]

  (void)hipMemsetAsync(cnt, 0, 2*4*SEQ*sizeof(int), stream);
  pack_w<<<4608, 256, 0, stream>>>(Wih, Whh, wpk);

  float* hn = out + 25165824;                        // [2][64][768]
  float* cn = out + 25165824 + 98304;

  const u32* wipk0 = wpk;
  const u32* wipk1 = wpk + (size_t)4608*512;
  const u32* whpk0 = wpk + (size_t)9216*512;
  const u32* whpk1 = wpk + (size_t)13824*512;

  lstm_scan<0, 0, 0><<<dim3(NWG), dim3(TPB), 0, stream>>>(
      x, nullptr, mask, wipk0, whpk0, bih, bhh,
      opk, opk, nullptr, hn, cn, cnt);

  if (big) {
    lstm_scan<1, 1, 0><<<dim3(NWG), dim3(TPB), 0, stream>>>(
        nullptr, opk, mask, wipk1, whpk1, bih + FH, bhh + FH,
        h1, h1, out, hn + 49152, cn + 49152, cnt + 4*SEQ);
  } else {
    lstm_scan<1, 1, 1><<<dim3(NWG), dim3(TPB), 0, stream>>>(
        nullptr, opk, mask, wipk1, whpk1, bih + FH, bhh + FH,
        h1, h1, out, hn + 49152, cn + 49152, cnt + 4*SEQ);
  }
}